// Round 4
// baseline (96.684 us; speedup 1.0000x reference)
//
#include <hip/hip_runtime.h>

// DropStripes (SpecAugment along time axis, dim=2).
// x: [B=64, C=1, T=4096, F=256] fp32; bgn, distance: [B, 2] int32.
// out = x * keep[b,t], keep = NOT any stripe covers t: t in [bgn, bgn+dist).
//
// Memory-bound masked copy (536.9 MB traffic).
// R2 (flat, 1 float4/thread): 94.0 µs = 5.71 TB/s (91% of 6.29 TB/s ceiling).
// R3: 2 float4/thread flat (512 consecutive float4 per block), int2 mask
//     loads — amortize block launch + mask-load overhead, keep flat layout.

typedef float v4f __attribute__((ext_vector_type(4)));

constexpr int T_DIM = 4096;          // time axis length
constexpr int ROW_SHIFT = 6;         // log2(64 float4 per row)
constexpr int T_SHIFT = 12;          // log2(T_DIM)

__device__ __forceinline__ v4f load_masked(const v4f* __restrict__ x,
                                           const int2* __restrict__ bgn,
                                           const int2* __restrict__ dist,
                                           int i) {
  const int row = i >> ROW_SHIFT;
  const int t = row & (T_DIM - 1);
  const int b = row >> T_SHIFT;
  const int2 bg = bgn[b];            // both stripes' starts, one 8B load
  const int2 ds = dist[b];           // both stripes' widths, one 8B load
  const bool drop = (t >= bg.x && t < bg.x + ds.x) ||
                    (t >= bg.y && t < bg.y + ds.y);
  v4f v = {0.f, 0.f, 0.f, 0.f};
  if (!drop) {                       // wave-uniform (wave == one t-row)
    v = x[i];
  }
  return v;
}

__global__ __launch_bounds__(256) void drop_stripes_kernel(
    const v4f*  __restrict__ x,
    const int2* __restrict__ bgn,
    const int2* __restrict__ dist,
    v4f*        __restrict__ out) {
  // Each block owns 512 consecutive float4s: two coalesced 256-wide chunks.
  const int base = blockIdx.x * 512 + threadIdx.x;
  v4f v0 = load_masked(x, bgn, dist, base);        // both loads issued
  v4f v1 = load_masked(x, bgn, dist, base + 256);  // before either store
  out[base] = v0;
  out[base + 256] = v1;
}

extern "C" void kernel_launch(void* const* d_in, const int* in_sizes, int n_in,
                              void* d_out, int out_size, void* d_ws, size_t ws_size,
                              hipStream_t stream) {
  const v4f*  x    = (const v4f*)d_in[0];
  const int2* bgn  = (const int2*)d_in[1];
  const int2* dist = (const int2*)d_in[2];
  v4f* out         = (v4f*)d_out;

  const int n4 = out_size / 4;        // 16,777,216 float4s (fixed shape)
  const int grid = n4 / 512;          // 32,768 blocks, exact cover, no tail
  drop_stripes_kernel<<<grid, 256, 0, stream>>>(x, bgn, dist, out);
}

// Round 5
// 88.919 us; speedup vs baseline: 1.0873x; 1.0873x over previous
//
#include <hip/hip_runtime.h>

// DropStripes (SpecAugment along time axis, dim=2).
// x: [B=64, C=1, T=4096, F=256] fp32; bgn, distance: [B, 2] int32.
// out = x * keep[b,t], keep = NOT any stripe covers t: t in [bgn, bgn+dist).
//
// Memory-bound masked copy (536.9 MB traffic).
// Ladder: R0 grid-stride 105.9 | R1 +unroll+nt 110.7 (regr) |
//         R2 flat 1xfloat4/thread 94.0 (5.71 TB/s, 91% of copy ceiling) |
//         R3 2xfloat4/thread 96.7 (regr).
// R4: R2 base + non-temporal load/store ONLY (unbundled A/B). Zero-reuse
//     streams, 512 MB footprint > L3 — skip cache allocation churn.

typedef float v4f __attribute__((ext_vector_type(4)));

constexpr int T_DIM = 4096;          // time axis length
constexpr int ROW_SHIFT = 6;         // log2(64 float4 per row)
constexpr int T_SHIFT = 12;          // log2(T_DIM)

__global__ __launch_bounds__(256) void drop_stripes_kernel(
    const v4f* __restrict__ x,
    const int* __restrict__ bgn,
    const int* __restrict__ dist,
    v4f*       __restrict__ out) {
  const int i = blockIdx.x * 256 + threadIdx.x;   // one float4 per thread
  const int row = i >> ROW_SHIFT;                 // global t-row index
  const int t = row & (T_DIM - 1);
  const int b = row >> T_SHIFT;

  // Per-sample stripe table (1 KB total) — L1-resident; b is wave-uniform
  // (one wave == one t-row), so the branch is non-divergent.
  const int b0 = bgn[b * 2 + 0], b1 = bgn[b * 2 + 1];
  const int d0 = dist[b * 2 + 0], d1 = dist[b * 2 + 1];
  const bool drop = (t >= b0 && t < b0 + d0) || (t >= b1 && t < b1 + d1);

  v4f v = {0.f, 0.f, 0.f, 0.f};
  if (!drop) {
    v = __builtin_nontemporal_load(&x[i]);
  }
  __builtin_nontemporal_store(v, &out[i]);
}

extern "C" void kernel_launch(void* const* d_in, const int* in_sizes, int n_in,
                              void* d_out, int out_size, void* d_ws, size_t ws_size,
                              hipStream_t stream) {
  const v4f* x    = (const v4f*)d_in[0];
  const int* bgn  = (const int*)d_in[1];
  const int* dist = (const int*)d_in[2];
  v4f* out        = (v4f*)d_out;

  const int n4 = out_size / 4;        // 16,777,216 float4s (fixed shape)
  const int block = 256;
  const int grid = n4 / block;        // 65,536 blocks, exact cover, no tail
  drop_stripes_kernel<<<grid, block, 0, stream>>>(x, bgn, dist, out);
}